// Round 7
// baseline (383.645 us; speedup 1.0000x reference)
//
#include <hip/hip_runtime.h>
#include <stdint.h>

typedef unsigned short u16;
typedef short short8 __attribute__((ext_vector_type(8)));
typedef float floatx4 __attribute__((ext_vector_type(4)));

#define NPERB   40000
#define NPTS    80000
#define KNBR    16
#define CIN     64
#define MDIM    16
#define CADD    3
#define CF      (CIN + CADD)
#define COUT    128
#define KF      1072
#define KP      1088
#define NKT     34        // KP/32 K-steps
#define PTSB    16        // fused-fallback: points per block
#define SLAB    65        // fused-fallback: chunks per kt slab
#define GRB     32        // gemm: rows per block
#define PPB     8         // pconv: points per block (4 waves x 2)
#define LROWB   2192      // gemm LDS row pitch bytes (548 dwords, %32==4)

__device__ __forceinline__ u16 f2bf(float f) {
    union { float f; unsigned int u; } v; v.f = f;
    unsigned int u = v.u;
    return (u16)((u + 0x7FFFu + ((u >> 16) & 1u)) >> 16);
}
__device__ __forceinline__ short8 pack8(floatx4 x, floatx4 y) {
    union { short8 v; u16 a[8]; } u;
    u.a[0] = f2bf(x[0]); u.a[1] = f2bf(x[1]); u.a[2] = f2bf(x[2]); u.a[3] = f2bf(x[3]);
    u.a[4] = f2bf(y[0]); u.a[5] = f2bf(y[1]); u.a[6] = f2bf(y[2]); u.a[7] = f2bf(y[3]);
    return u.v;
}
// fused-fallback swizzle (16B-chunk XOR)
__device__ __forceinline__ unsigned swz(unsigned chunk) {
    return chunk ^ ((chunk >> 3) & 7u);
}
// async global -> LDS, 16B per lane; LDS dest = uniform base + lane*16 (linear).
__device__ __forceinline__ void gload_lds16(const void* g, void* l) {
    __builtin_amdgcn_global_load_lds(
        (const __attribute__((address_space(1))) void*)g,
        (__attribute__((address_space(3))) void*)l, 16, 0, 0);
}

// Convert+pad linear_weight fp32 [128,1072] -> bf16 ws [128,1088] (zero pad).
__global__ void prep_lw_kernel(const float* __restrict__ lw, u16* __restrict__ lwp) {
    int i = blockIdx.x * 256 + threadIdx.x;
    if (i >= COUT * KP) return;
    int o = i / KP, f = i - o * KP;
    lwp[i] = (f < KF) ? f2bf(lw[(size_t)o * KF + f]) : (u16)0;
}

// ============================ SPLIT PATH ============================
// Kernel 1: pconv (UNCHANGED).
__device__ __forceinline__ void emit_point(
    int lane, float av, const float (&fv)[KNBR], const float* wl,
    u16* __restrict__ dst)
{
    const int em = lane & 15, ec = lane >> 4;
    float ev = 0.f;
#pragma unroll
    for (int k = 0; k < KNBR; k++)
        ev += __shfl(av, k * CADD + ec) * wl[k * MDIM + em];
    if (ec == 3) ev = 0.f;                       // channel 67 + f>=1072 pad
    dst[1024 + lane] = f2bf(ev);

    floatx4 a0 = 0, a1 = 0, a2 = 0, a3 = 0;
#pragma unroll
    for (int k = 0; k < KNBR; k++) {
        const floatx4* w4 = (const floatx4*)(wl + k * MDIM);  // uniform -> bcast
        const float fvk = fv[k];
        a0 += fvk * w4[0]; a1 += fvk * w4[1];
        a2 += fvk * w4[2]; a3 += fvk * w4[3];
    }
    *(short8*)(dst + lane * 16)     = pack8(a0, a1);   // m 0..7
    *(short8*)(dst + lane * 16 + 8) = pack8(a2, a3);   // m 8..15
}

__global__ __launch_bounds__(256) void pconv_kernel(
    const float* __restrict__ inp,   // [2,40000,64] fp32
    const int*   __restrict__ nbr,   // [2,40000,16] int32
    const float* __restrict__ wn,    // [2,40000,16,16] fp32
    const float* __restrict__ addl,  // [2,40000,16,3] fp32
    u16* __restrict__ pc)            // [80000,1088] bf16
{
    __shared__ __align__(16) float Wns[PPB * KNBR * MDIM];   // 8KB

    const int wave = threadIdx.x >> 6;
    const int lane = threadIdx.x & 63;
    const int pbase = blockIdx.x * PPB;         // 40000 % 8 == 0
    const float* inpb = inp + ((pbase >= NPERB) ? (size_t)NPERB * CIN : 0);

    const int pr0 = wave * 2;
    const int p0  = __builtin_amdgcn_readfirstlane(pbase + pr0);
    const int p1  = p0 + 1;

    float* wl0 = Wns + pr0 * (KNBR * MDIM);
    float* wl1 = wl0 + KNBR * MDIM;
    gload_lds16(wn + (size_t)p0 * (KNBR * MDIM) + lane * 4, wl0);
    gload_lds16(wn + (size_t)p1 * (KNBR * MDIM) + lane * 4, wl1);

    float av0 = (lane < KNBR * CADD) ? addl[(size_t)p0 * (KNBR * CADD) + lane] : 0.f;
    float av1 = (lane < KNBR * CADD) ? addl[(size_t)p1 * (KNBR * CADD) + lane] : 0.f;

    const int* nb0 = nbr + (size_t)p0 * KNBR;   // uniform -> s_loads
    const int* nb1 = nbr + (size_t)p1 * KNBR;
    int idx0[KNBR], idx1[KNBR];
#pragma unroll
    for (int k = 0; k < KNBR; k++) idx0[k] = nb0[k];
#pragma unroll
    for (int k = 0; k < KNBR; k++) idx1[k] = nb1[k];

    float fv0[KNBR], fv1[KNBR];
#pragma unroll
    for (int k = 0; k < KNBR; k++) fv0[k] = inpb[(size_t)idx0[k] * CIN + lane];
#pragma unroll
    for (int k = 0; k < KNBR; k++) fv1[k] = inpb[(size_t)idx1[k] * CIN + lane];

    asm volatile("s_waitcnt vmcnt(0)" ::: "memory");  // wn staging + gathers
    __builtin_amdgcn_sched_barrier(0);

    emit_point(lane, av0, fv0, wl0, pc + (size_t)p0 * KP);
    emit_point(lane, av1, fv1, wl1, pc + (size_t)p1 * KP);
}

// Kernel 2 (r7): GEMM [80000 x 1088]bf16 x [1088 x 128]bf16 -> fp32 (+bias).
// r6 post-mortem: every prior gemm fetched A as 64B-per-row granules at
// 2176B stride (16 cache lines / instr) -> A-path throughput capped ~2-3
// TB/s; queue depth became queuing delay (4000 cyc/step). r7: stage the
// block's ENTIRE A-tile (32 rows = 69.6KB, contiguous in pc) with 69
// linear 1KB gload_lds, ONE vmcnt(0)+barrier per block. K-loop reads A
// from LDS only; B = depth-3 register pipeline from L2 (counted vmcnt(8)).
// LDS rows padded to 2192B (548 dw %32 = 4) via per-lane SOURCE unpadding
// (dest linear, m104/m173) -> b128 reads conflict-free. 2 blocks/CU; the
// next block's bulk staging overlaps this block's compute at CU level.
__global__ __launch_bounds__(256) void gemm_kernel(
    const u16* __restrict__ pc,     // [80000,1088] bf16 (FIRST in ws)
    const u16* __restrict__ lwp,    // [128,1088] bf16
    const float* __restrict__ bias, // [128] fp32
    float* __restrict__ out)        // [80000,128] fp32
{
    __shared__ __align__(16) u16 As[69 * 512];     // 69 KB-windows = 70656 B

    const int wave = threadIdx.x >> 6;
    const int lane = threadIdx.x & 63;
    const int r16 = lane & 15, quad = lane >> 4;
    const int rh = wave >> 1, ch = wave & 1;       // row-half / col-half
    const int row0 = blockIdx.x * GRB;
    const int cb = ch * 64;

    // ---- bulk A staging: contiguous source, padded LDS rows ----
    const char* srcb = (const char*)pc + (size_t)row0 * (KP * 2);
#pragma unroll
    for (int j = 0; j < 18; j++) {
        const int w = j * 4 + wave;                // 69 windows over 4 waves
        if (w < 69) {
            const unsigned d   = (unsigned)w * 1024u + (unsigned)lane * 16u;
            const unsigned row = d / (unsigned)LROWB;          // magic-mul
            const unsigned col = d - row * (unsigned)LROWB;
            // col>=2176 (pad) reads start of next row: in-bounds (lwp after pc)
            gload_lds16(srcb + (size_t)row * 2176u + col,
                        (char*)As + (size_t)w * 1024u);
        }
    }

    // B fragment bases: row cb + n*16 + r16, col quad*8 (+kt*32)
    const u16* bB0 = lwp + (size_t)(cb + r16) * KP + quad * 8;
    const u16* bB1 = bB0 + (size_t)16 * KP;
    const u16* bB2 = bB0 + (size_t)32 * KP;
    const u16* bB3 = bB0 + (size_t)48 * KP;

    float bv[4];
#pragma unroll
    for (int n = 0; n < 4; n++) bv[n] = bias[cb + n * 16 + r16];

    // A reader base (u16 units): row rh*16+r16, chunk quad; +32 per kt
    const u16* aRd = As + (size_t)(rh * 16 + r16) * (LROWB / 2) + quad * 8;

    floatx4 acc[4];
#pragma unroll
    for (int n = 0; n < 4; n++) acc[n] = 0;

    short8 Bq[3][4];          // static-indexed after full unroll
    short8 AR0, AR1;          // A double buffer (kt&1)

#define LOADB(t) { \
    Bq[(t) % 3][0] = *(const short8*)(bB0 + (t) * 32); \
    Bq[(t) % 3][1] = *(const short8*)(bB1 + (t) * 32); \
    Bq[(t) % 3][2] = *(const short8*)(bB2 + (t) * 32); \
    Bq[(t) % 3][3] = *(const short8*)(bB3 + (t) * 32); }

    LOADB(0)
    __builtin_amdgcn_sched_barrier(0);
    LOADB(1)
    __builtin_amdgcn_sched_barrier(0);

    // staging complete (own waves' vmcnt; barrier covers all waves)
    asm volatile("s_waitcnt vmcnt(8)" ::: "memory");   // 8 = B(0)+B(1) remain
    __syncthreads();
    AR0 = *(const short8*)aRd;                         // A(0)

    // steady: wait vmcnt(8) = {B(kt+1), B(kt+2)} in flight, B(kt) retired.
    // lgkmcnt(1) = A(kt+1) in flight, A(kt) retired.
#define STEP(kt, NV, NL) { \
    if ((kt) + 2 < NKT) { LOADB((kt) + 2) __builtin_amdgcn_sched_barrier(0); } \
    if ((kt) + 1 < NKT) { \
        if ((((kt) + 1) & 1) == 0) AR0 = *(const short8*)(aRd + ((kt) + 1) * 32); \
        else                       AR1 = *(const short8*)(aRd + ((kt) + 1) * 32); \
    } \
    __builtin_amdgcn_sched_barrier(0); \
    asm volatile("s_waitcnt vmcnt(" #NV ") lgkmcnt(" #NL ")" ::: "memory"); \
    __builtin_amdgcn_sched_barrier(0); \
    _Pragma("unroll") \
    for (int n = 0; n < 4; n++) \
        acc[n] = __builtin_amdgcn_mfma_f32_16x16x32_bf16( \
            (((kt) & 1) == 0) ? AR0 : AR1, Bq[(kt) % 3][n], acc[n], 0, 0, 0); }

    STEP(0, 8, 1)  STEP(1, 8, 1)  STEP(2, 8, 1)  STEP(3, 8, 1)  STEP(4, 8, 1)
    STEP(5, 8, 1)  STEP(6, 8, 1)  STEP(7, 8, 1)  STEP(8, 8, 1)  STEP(9, 8, 1)
    STEP(10, 8, 1) STEP(11, 8, 1) STEP(12, 8, 1) STEP(13, 8, 1) STEP(14, 8, 1)
    STEP(15, 8, 1) STEP(16, 8, 1) STEP(17, 8, 1) STEP(18, 8, 1) STEP(19, 8, 1)
    STEP(20, 8, 1) STEP(21, 8, 1) STEP(22, 8, 1) STEP(23, 8, 1) STEP(24, 8, 1)
    STEP(25, 8, 1) STEP(26, 8, 1) STEP(27, 8, 1) STEP(28, 8, 1) STEP(29, 8, 1)
    STEP(30, 8, 1) STEP(31, 8, 1) STEP(32, 4, 1) STEP(33, 0, 0)

#undef STEP
#undef LOADB

    // epilogue: D[row=quad*4+r][col=r16]; 4 n-stores back-to-back = 256B/row
#pragma unroll
    for (int r = 0; r < 4; r++) {
        const size_t row = (size_t)(row0 + rh * 16 + quad * 4 + r) * COUT;
#pragma unroll
        for (int n = 0; n < 4; n++)
            out[row + cb + n * 16 + r16] = acc[n][r] + bv[n];
    }
}

// ===================== FUSED FALLBACK (r1 kernel) =====================
__device__ __forceinline__ void compute_point(
    int pr, int lane, float av, const float (&fv)[KNBR],
    const float* wl, u16* Apc)
{
    const int em = lane & 15, ec = lane >> 4;
    float ev = 0.f;
#pragma unroll
    for (int k = 0; k < KNBR; k++)
        ev += __shfl(av, k * CADD + ec) * wl[k * MDIM + em];
    if (ec == 3) ev = 0.f;
    {
        unsigned kt   = 32 + (lane >> 5);
        unsigned quad = (lane >> 3) & 3;
        unsigned ch   = kt * SLAB + (unsigned)pr * 4 + quad;
        Apc[swz(ch) * 8 + (lane & 7)] = f2bf(ev);
    }
    floatx4 a0 = 0, a1 = 0, a2 = 0, a3 = 0;
#pragma unroll
    for (int k = 0; k < KNBR; k++) {
        const floatx4* w4 = (const floatx4*)(wl + k * MDIM);
        const float fvk = fv[k];
        a0 += fvk * w4[0]; a1 += fvk * w4[1];
        a2 += fvk * w4[2]; a3 += fvk * w4[3];
    }
    {
        unsigned kt = lane >> 1, qb = (lane & 1) * 2;
        unsigned ch = kt * SLAB + (unsigned)pr * 4 + qb;
        *(short8*)&Apc[swz(ch) * 8]     = pack8(a0, a1);
        *(short8*)&Apc[swz(ch + 1) * 8] = pack8(a2, a3);
    }
}

__global__ __launch_bounds__(512, 6) void fused_kernel(
    const float* __restrict__ inp, const int* __restrict__ nbr,
    const float* __restrict__ wn, const float* __restrict__ addl,
    const u16* __restrict__ lwp, const float* __restrict__ bias,
    float* __restrict__ out)
{
    __shared__ __align__(16) u16   Apc[(NKT * SLAB + 8) * 8];
    __shared__ __align__(16) float Wns[PTSB * KNBR * MDIM];

    const int wave = threadIdx.x >> 6;
    const int lane = threadIdx.x & 63;
    const int pbase = blockIdx.x * PTSB;
    const float* inpb = inp + ((pbase >= NPERB) ? (size_t)NPERB * CIN : 0);

    const int pr0 = wave * 2;
    const int p0  = __builtin_amdgcn_readfirstlane(pbase + pr0);
    const int p1  = p0 + 1;

    float* wl0 = Wns + pr0 * (KNBR * MDIM);
    float* wl1 = wl0 + KNBR * MDIM;
    gload_lds16(wn + (size_t)p0 * (KNBR * MDIM) + lane * 4, wl0);
    gload_lds16(wn + (size_t)p1 * (KNBR * MDIM) + lane * 4, wl1);

    float av0 = (lane < KNBR * CADD) ? addl[(size_t)p0 * (KNBR * CADD) + lane] : 0.f;
    float av1 = (lane < KNBR * CADD) ? addl[(size_t)p1 * (KNBR * CADD) + lane] : 0.f;

    const int* nb0 = nbr + (size_t)p0 * KNBR;
    const int* nb1 = nbr + (size_t)p1 * KNBR;
    int idx0[KNBR], idx1[KNBR];
#pragma unroll
    for (int k = 0; k < KNBR; k++) idx0[k] = nb0[k];
#pragma unroll
    for (int k = 0; k < KNBR; k++) idx1[k] = nb1[k];

    float fv0[KNBR], fv1[KNBR];
#pragma unroll
    for (int k = 0; k < KNBR; k++) fv0[k] = inpb[(size_t)idx0[k] * CIN + lane];
#pragma unroll
    for (int k = 0; k < KNBR; k++) fv1[k] = inpb[(size_t)idx1[k] * CIN + lane];

    asm volatile("s_waitcnt vmcnt(0)" ::: "memory");
    __builtin_amdgcn_sched_barrier(0);

    compute_point(pr0,     lane, av0, fv0, wl0, Apc);
    compute_point(pr0 + 1, lane, av1, fv1, wl1, Apc);

    const int r16 = lane & 15, quad = lane >> 4;
    const int c0 = wave * 16;
    const u16* Bp = lwp + (size_t)(c0 + r16) * KP + quad * 8;
    const unsigned abase = (unsigned)r16 * 4 + quad;
    const float bv = bias[c0 + r16];

    __syncthreads();

    floatx4 acc = 0;
#pragma unroll 2
    for (int kt = 0; kt < NKT; kt++) {
        short8 A = *(const short8*)&Apc[swz((unsigned)kt * SLAB + abase) * 8];
        short8 B = *(const short8*)(Bp + kt * 32);
        acc = __builtin_amdgcn_mfma_f32_16x16x32_bf16(A, B, acc, 0, 0, 0);
    }

#pragma unroll
    for (int r = 0; r < 4; r++) {
        const size_t row = (size_t)(pbase + quad * 4 + r) * COUT;
        out[row + c0 + r16] = acc[r] + bv;
    }
}

// Slow last-resort fallback: all-fp32, one block per point.
__global__ __launch_bounds__(256) void fused_fallback_kernel(
    const float* __restrict__ inp, const int* __restrict__ nbr,
    const float* __restrict__ wn, const float* __restrict__ addl,
    const float* __restrict__ lw, const float* __restrict__ bias,
    float* __restrict__ out)
{
    const int p = blockIdx.x;
    const int b = p / NPERB;
    const int tid = threadIdx.x;
    __shared__ float sf[KNBR * CF];
    __shared__ float sw[KNBR * MDIM];
    __shared__ float sp[KF];

    sw[tid] = wn[(size_t)p * (KNBR * MDIM) + tid];
    for (int i = tid; i < KNBR * CIN; i += 256) {
        int k = i >> 6, c = i & 63;
        int idx = nbr[(size_t)p * KNBR + k];
        sf[k * CF + c] = inp[((size_t)b * NPERB + idx) * CIN + c];
    }
    if (tid < KNBR * CADD) {
        int k = tid / CADD, c = tid - k * CADD;
        sf[k * CF + CIN + c] = addl[(size_t)p * (KNBR * CADD) + tid];
    }
    __syncthreads();
    for (int f = tid; f < KF; f += 256) {
        int c = f >> 4, m = f & 15;
        float s = 0;
#pragma unroll
        for (int k = 0; k < KNBR; k++) s += sf[k * CF + c] * sw[k * MDIM + m];
        sp[f] = s;
    }
    __syncthreads();
    const int o = tid >> 1, h = tid & 1;
    float s = 0;
    for (int f = h * (KF / 2); f < (h + 1) * (KF / 2); f++)
        s += sp[f] * lw[(size_t)o * KF + f];
    s += __shfl_xor(s, 1);
    if (h == 0) out[(size_t)p * COUT + o] = s + bias[o];
}

extern "C" void kernel_launch(void* const* d_in, const int* in_sizes, int n_in,
                              void* d_out, int out_size, void* d_ws, size_t ws_size,
                              hipStream_t stream) {
    const float* inp  = (const float*)d_in[0];
    const int*   nbr  = (const int*)d_in[1];
    // d_in[2..4] = inverse_* (backward-only, unused)
    const float* wn   = (const float*)d_in[5];
    const float* addl = (const float*)d_in[6];
    const float* lw   = (const float*)d_in[7];
    const float* bias = (const float*)d_in[8];
    float* out = (float*)d_out;

    const size_t lw_bytes = (size_t)COUT * KP * sizeof(u16);   // 278,528
    const size_t pc_bytes = (size_t)NPTS * KP * sizeof(u16);   // 174,080,000

    if (ws_size >= lw_bytes + pc_bytes) {
        // pc FIRST so gemm's <=496B staging overread lands in lwp (in-bounds)
        u16* pcw = (u16*)d_ws;
        u16* lwp = pcw + (size_t)NPTS * KP;
        prep_lw_kernel<<<(COUT * KP + 255) / 256, 256, 0, stream>>>(lw, lwp);
        pconv_kernel<<<NPTS / PPB, 256, 0, stream>>>(inp, nbr, wn, addl, pcw);
        gemm_kernel<<<NPTS / GRB, 256, 0, stream>>>(pcw, lwp, bias, out);
    } else if (ws_size >= lw_bytes) {
        u16* lwp = (u16*)d_ws;
        prep_lw_kernel<<<(COUT * KP + 255) / 256, 256, 0, stream>>>(lw, lwp);
        fused_kernel<<<NPTS / PTSB, 512, 0, stream>>>(inp, nbr, wn, addl, lwp, bias, out);
    } else {
        fused_fallback_kernel<<<NPTS, 256, 0, stream>>>(inp, nbr, wn, addl, lw, bias, out);
    }
}